// Round 11
// baseline (680.386 us; speedup 1.0000x reference)
//
#include <hip/hip_runtime.h>

typedef unsigned int u32;
typedef unsigned short u16;
typedef unsigned long long u64;
typedef u16 u16x8 __attribute__((ext_vector_type(8)));
typedef u16 u16x4 __attribute__((ext_vector_type(4)));
typedef __bf16 bf16x8 __attribute__((ext_vector_type(8)));
typedef __bf16 bf16x4v __attribute__((ext_vector_type(4)));
typedef float f32x4 __attribute__((ext_vector_type(4)));
typedef float f32x2 __attribute__((ext_vector_type(2)));

#define B_SZ 32
#define S_SZ 128
#define T_SZ 127
#define DK 128
#define SKILL 256
#define SQTR 64     /* skills per scan block (4-way split) */
#define RL 136      /* hS row pitch (u16): 128 + 8 pad */
#define PP 68       /* part row pitch (f32): 64 + 4 pad */
#define SLOTS 4     /* packet ring depth (scan-exchange ONLY) */
#define SLOTM 3
#define SPIN_CAP (1 << 18)

/* repacked-weight offsets (floats), chunk-major WT[(k4*128+o)*4+j] */
#define W1T_OFF 0        /* 96 chunks  */
#define WLT_OFF 49152    /* 128 chunks */
#define WGT_OFF 114688   /* 128 chunks */
#define WFT_OFF 180224   /* 96 chunks  */
#define WPT_OFF 229376   /* 64 chunks  */
#define WT_TOTAL 262144

__device__ __forceinline__ u16x4 cvt4(f32x4 v) {
    return __builtin_bit_cast(u16x4, __builtin_convertvector(v, bf16x4v));
}
__device__ __forceinline__ u16x8 cvt8(f32x4 a, f32x4 b) {
    u16x4 x = cvt4(a), y = cvt4(b);
    u16x8 r;
    r[0]=x[0]; r[1]=x[1]; r[2]=x[2]; r[3]=x[3];
    r[4]=y[0]; r[5]=y[1]; r[6]=y[2]; r[7]=y[3];
    return r;
}
__device__ __forceinline__ u16 bfu(float x) {
    return __builtin_bit_cast(u16, (__bf16)x);
}
__device__ __forceinline__ float sigm(float x) {
    float e = __builtin_amdgcn_exp2f(-1.44269504f * x);
    return __builtin_amdgcn_rcpf(1.f + e);
}
__device__ __forceinline__ float tanh_f(float x) {
    float e = __builtin_amdgcn_exp2f(-2.88539008f * x);
    return 2.f * __builtin_amdgcn_rcpf(1.f + e) - 1.f;
}
__device__ __forceinline__ f32x4 mfma16(u16x8 a, u16x8 bb, f32x4 c) {
    return __builtin_amdgcn_mfma_f32_16x16x32_bf16(
        __builtin_bit_cast(bf16x8, a), __builtin_bit_cast(bf16x8, bb), c, 0, 0, 0);
}
__device__ __forceinline__ float pval(u64 p) {
    return __builtin_bit_cast(float, (u32)p);
}
__device__ __forceinline__ float dot4(f32x4 w, f32x4 x) {
    return w[0] * x[0] + w[1] * x[1] + w[2] * x[2] + w[3] * x[3];
}
__device__ __forceinline__ float aldf(const float* p) {
    return __hip_atomic_load(p, __ATOMIC_RELAXED, __HIP_MEMORY_SCOPE_AGENT);
}
__device__ __forceinline__ void astf(float* p, float v) {
    __hip_atomic_store(p, v, __ATOMIC_RELAXED, __HIP_MEMORY_SCOPE_AGENT);
}
__device__ __forceinline__ u64 ald64(const u64* p) {
    return __hip_atomic_load(p, __ATOMIC_RELAXED, __HIP_MEMORY_SCOPE_AGENT);
}
__device__ __forceinline__ void ast64(u64* p, u64 v) {
    __hip_atomic_store(p, v, __ATOMIC_RELAXED, __HIP_MEMORY_SCOPE_AGENT);
}

// ---------------------------------------------------------------------------
// Kernel P: repack W1/Wl/Wg/Wf/Wp into chunk-major WT (lane-consecutive).
// ---------------------------------------------------------------------------
__global__ __launch_bounds__(256) void k_prep(
    const float* __restrict__ W1, const float* __restrict__ Wl,
    const float* __restrict__ Wg, const float* __restrict__ Wf,
    const float* __restrict__ Wp, float* __restrict__ WT)
{
    int i = blockIdx.x * 256 + threadIdx.x;      // < 262144
    int j = i & 3, o = (i >> 2) & 127, k4 = i >> 9;
    float v;
    if (k4 < 96)        v = W1[o * 384 + 4 * k4 + j];
    else if (k4 < 224)  v = Wl[o * 512 + 4 * (k4 - 96) + j];
    else if (k4 < 352)  v = Wg[o * 512 + 4 * (k4 - 224) + j];
    else if (k4 < 448)  v = Wf[o * 384 + 4 * (k4 - 352) + j];
    else                v = Wp[o * 256 + 4 * (k4 - 448) + j];
    WT[i] = v;
}

// ---------------------------------------------------------------------------
// Mono-kernel. grid (B, 8): y in [0,4) = scan quarter qid (R5/R8 proven
// structure, unchanged); y in [4,8) = producer p = y-4 owning t-chunk
// [32p, min(32p+32,127)). Producers: le (LDS) -> PRE groups of 4 t
// (atomic stores + vmcnt + flag) with COALESCED WT weights, then pred for
// their chunk consuming the scan's h~ via WRITE-ONCE f32 journal
// (qid-0: stores -> vmcnt drain -> barrier -> flag). Packet ring is used
// ONLY for the lock-stepped scan<->scan exchange.
// ---------------------------------------------------------------------------
__global__ __launch_bounds__(512, 1) void k_mono(
    const int* __restrict__ eid, const int* __restrict__ atime,
    const int* __restrict__ itime, const int* __restrict__ ansv,
    const float* __restrict__ qmat, const float* __restrict__ ex_t,
    const float* __restrict__ at_t, const float* __restrict__ it_t,
    const float* __restrict__ WT, const float* __restrict__ b1,
    const float* __restrict__ Wl, const float* __restrict__ blv,
    const float* __restrict__ Wg, const float* __restrict__ bgv,
    const float* __restrict__ Wf, const float* __restrict__ bfv,
    const float* __restrict__ bpv, const float* __restrict__ h0,
    float* __restrict__ PRE_l, float* __restrict__ PRE_g, float* __restrict__ PRE_f,
    float* __restrict__ out, u64* __restrict__ xbuf, float* __restrict__ jrnF,
    int* __restrict__ jflg, int* __restrict__ flagsP)
{
    extern __shared__ char smem[];
    const int b    = blockIdx.x;
    const int role = blockIdx.y;
    const int tid  = threadIdx.x;
    u64* xq = xbuf + (size_t)b * (4 * SLOTS * 128);

    if (role < 4) {
        // ================= SCAN (R5/R8 structure, unchanged) =================
        u16*   hS   = (u16*)smem;                    // 64*136*2  = 17408
        float* part = (float*)(smem + 17408);        // 128*68*4  -> 52224
        u16*   htbf = (u16*)(smem + 52224);          // -> 52736
        u16*   LGb  = (u16*)(smem + 52736);          // -> 53248
        float* LGf  = (float*)(smem + 53248);        // -> 53760
        float* cS   = (float*)(smem + 53760);        // -> 54272

        const int qid  = role;
        const int w    = tid >> 6;
        const int lane = tid & 63;
        const int quad = lane >> 4;
        const int l4   = lane & 15;
        const int ih   = w & 1;
        const int jh   = w >> 1;
        const int qa = (qid + 1) & 3, qb2 = (qid + 2) & 3, qc = (qid + 3) & 3;

        u16x8 afr[4][4];
        #pragma unroll
        for (int mt = 0; mt < 4; ++mt)
            #pragma unroll
            for (int kt = 0; kt < 4; ++kt) {
                const float* p = Wf + (64 * ih + 16 * mt + l4) * 384 + 32 * kt + quad * 8;
                afr[mt][kt] = cvt8(*(const f32x4*)p, *(const f32x4*)(p + 4));
            }
        u16x8 azf[2][4];
        #pragma unroll
        for (int mt = 0; mt < 2; ++mt)
            #pragma unroll
            for (int kt = 0; kt < 4; ++kt) {
                int d = 16 * w + 8 * mt + (l4 >> 1);
                const float* base = (l4 & 1) ? Wg : Wl;
                const float* p = base + d * 512 + 384 + 32 * kt + quad * 8;
                azf[mt][kt] = cvt8(*(const f32x4*)p, *(const f32x4*)(p + 4));
            }
        u16x8 acf[4];
        #pragma unroll
        for (int kt = 0; kt < 4; ++kt) {
            const float* p = Wf + (16 * w + l4) * 384 + 128 + 32 * kt + quad * 8;
            acf[kt] = cvt8(*(const f32x4*)p, *(const f32x4*)(p + 4));
        }

        const int sl = 16 * jh + l4;
        f32x4 hreg[4];
        #pragma unroll
        for (int mt = 0; mt < 4; ++mt) {
            int d0 = 64 * ih + 16 * mt + quad * 4;
            f32x4 hv = *(const f32x4*)(h0 + (SQTR * qid + sl) * DK + d0);
            hreg[mt] = hv;
            *(u16x4*)(hS + sl * RL + d0) = cvt4(hv);
        }

        float kvt = qmat[eid[b * S_SZ] * SKILL + SQTR * qid + sl];
        f32x4 accF[4];

        {
            float htp[16];
            #pragma unroll
            for (int mt = 0; mt < 4; ++mt)
                #pragma unroll
                for (int r = 0; r < 4; ++r)
                    htp[mt * 4 + r] = kvt * hreg[mt][r];
            #pragma unroll
            for (int mt = 0; mt < 4; ++mt)
                #pragma unroll
                for (int r = 0; r < 4; ++r)
                    part[(64 * ih + 16 * mt + quad * 4 + r) * PP + jh * 16 + l4] = htp[mt * 4 + r];
            __syncthreads();
            int d = tid >> 2, kq = tid & 3;
            const float* pp = part + d * PP + kq * 16;
            float v = 0.f;
            #pragma unroll
            for (int i4 = 0; i4 < 4; ++i4) {
                f32x4 x = *(const f32x4*)(pp + 4 * i4);
                v += x[0] + x[1] + x[2] + x[3];
            }
            v += __shfl_xor(v, 1, 64);
            v += __shfl_xor(v, 2, 64);
            if (kq == 0)
                ast64(xq + qid * (SLOTS * 128) + 1 * 128 + d,
                      ((u64)1u << 32) | (u64)__builtin_bit_cast(u32, v));
            asm volatile("" ::: "memory");
            #pragma unroll
            for (int mt = 0; mt < 4; ++mt)
                accF[mt] = (f32x4){0.f, 0.f, 0.f, 0.f};
            {
                const u16* bp2 = hS + sl * RL + quad * 8;
                u16x8 bfr[4];
                #pragma unroll
                for (int kt = 0; kt < 4; ++kt) bfr[kt] = *(const u16x8*)(bp2 + kt * 32);
                #pragma unroll
                for (int mt = 0; mt < 4; ++mt)
                    #pragma unroll
                    for (int kt = 0; kt < 4; ++kt)
                        accF[mt] = mfma16(afr[mt][kt], bfr[kt], accF[mt]);
            }
            if (kq == 0) {
                u64 pa, pb, pc2;
                int spins = 0;
                do {
                    pa  = ald64(xq + qa  * (SLOTS * 128) + 128 + d);
                    pb  = ald64(xq + qb2 * (SLOTS * 128) + 128 + d);
                    pc2 = ald64(xq + qc  * (SLOTS * 128) + 128 + d);
                    if ((u32)(pa >> 32) >= 1u && (u32)(pb >> 32) >= 1u && (u32)(pc2 >> 32) >= 1u) break;
                    if (spins > 64) __builtin_amdgcn_s_sleep(1);
                } while (++spins < SPIN_CAP);
                float va = pval(pa), vb = pval(pb), vc = pval(pc2);
                float v0 = (qid == 0) ? v : (qid == 3) ? va : (qid == 2) ? vb : vc;
                float v1 = (qid == 1) ? v : (qid == 0) ? va : (qid == 3) ? vb : vc;
                float v2 = (qid == 2) ? v : (qid == 1) ? va : (qid == 0) ? vb : vc;
                float v3 = (qid == 3) ? v : (qid == 2) ? va : (qid == 1) ? vb : vc;
                float vt = ((v0 + v1) + v2) + v3;
                float hf = (float)(__bf16)vt;
                htbf[d] = bfu(vt);
                htbf[128 + d] = bfu(vt - hf);
            }
            __syncthreads();
        }

        for (int t = 0; t < T_SZ; ++t) {
            const size_t tb = (size_t)(b * T_SZ + t) * DK;

            if ((t & 3) == 0) {
                const int gI = t >> 2;
                int spins = 0;
                while (__hip_atomic_load(flagsP + b * 32 + gI,
                                         __ATOMIC_RELAXED, __HIP_MEMORY_SCOPE_AGENT) == 0) {
                    if (spins > 16) __builtin_amdgcn_s_sleep(1);
                    if (++spins > SPIN_CAP) break;
                }
            }

            float kvn = qmat[eid[b * S_SZ + t + 1] * SKILL + SQTR * qid + sl];
            float plv[2][2], pgv[2][2], pfv[4];
            #pragma unroll
            for (int mt = 0; mt < 2; ++mt) {
                int d0 = 16 * w + 8 * mt + 2 * quad;
                plv[mt][0] = aldf(PRE_l + tb + d0);
                plv[mt][1] = aldf(PRE_l + tb + d0 + 1);
                pgv[mt][0] = aldf(PRE_g + tb + d0);
                pgv[mt][1] = aldf(PRE_g + tb + d0 + 1);
            }
            #pragma unroll
            for (int r = 0; r < 4; ++r)
                pfv[r] = aldf(PRE_f + tb + 16 * w + 4 * quad + r);

            f32x4 accZ[2];
            accZ[0] = (f32x4){0.f, 0.f, 0.f, 0.f};
            accZ[1] = (f32x4){0.f, 0.f, 0.f, 0.f};
            #pragma unroll
            for (int kt = 0; kt < 4; ++kt) {
                u16x8 bh = *(const u16x8*)(htbf + 32 * kt + quad * 8);
                u16x8 bl = *(const u16x8*)(htbf + 128 + 32 * kt + quad * 8);
                #pragma unroll
                for (int mt = 0; mt < 2; ++mt) {
                    accZ[mt] = mfma16(azf[mt][kt], bh, accZ[mt]);
                    accZ[mt] = mfma16(azf[mt][kt], bl, accZ[mt]);
                }
            }
            #pragma unroll
            for (int mt = 0; mt < 2; ++mt) {
                u32 hpack = 0, lpack = 0;
                f32x2 fpack;
                #pragma unroll
                for (int rp = 0; rp < 2; ++rp) {
                    float zl = accZ[mt][2 * rp] + plv[mt][rp];
                    float zg = accZ[mt][2 * rp + 1] + pgv[mt][rp];
                    float LGv = sigm(zg) * (tanh_f(zl) + 1.f) * 0.5f;
                    float hif = (float)(__bf16)LGv;
                    hpack |= ((u32)bfu(LGv)) << (16 * rp);
                    lpack |= ((u32)bfu(LGv - hif)) << (16 * rp);
                    fpack[rp] = LGv;
                }
                if (l4 == 0) {
                    int d0 = 16 * w + 8 * mt + 2 * quad;
                    *(u32*)(LGb + d0) = hpack;
                    *(u32*)(LGb + 128 + d0) = lpack;
                    *(f32x2*)(LGf + d0) = fpack;
                }
            }
            __syncthreads();   // B

            {
                f32x4 accC = (f32x4){0.f, 0.f, 0.f, 0.f};
                #pragma unroll
                for (int kt = 0; kt < 4; ++kt) {
                    u16x8 bh = *(const u16x8*)(LGb + 32 * kt + quad * 8);
                    u16x8 bl = *(const u16x8*)(LGb + 128 + 32 * kt + quad * 8);
                    accC = mfma16(acf[kt], bh, accC);
                    accC = mfma16(acf[kt], bl, accC);
                }
                #pragma unroll
                for (int r = 0; r < 4; ++r) accC[r] += pfv[r];
                if (l4 == 0) *(f32x4*)(cS + 16 * w + quad * 4) = accC;
            }
            __syncthreads();   // C

            float htp[16];
            #pragma unroll
            for (int mt = 0; mt < 4; ++mt) {
                int d0 = 64 * ih + 16 * mt + quad * 4;
                f32x4 lg = *(const f32x4*)(LGf + d0);
                f32x4 cc = *(const f32x4*)(cS + d0);
                f32x4 hv;
                #pragma unroll
                for (int r = 0; r < 4; ++r) {
                    float f = sigm(accF[mt][r] + cc[r]);
                    float hn = kvt * lg[r] + f * hreg[mt][r];
                    hreg[mt][r] = hn;
                    htp[mt * 4 + r] = kvn * hn;
                    hv[r] = hn;
                }
                *(u16x4*)(hS + sl * RL + d0) = cvt4(hv);
            }
            #pragma unroll
            for (int mt = 0; mt < 4; ++mt)
                #pragma unroll
                for (int r = 0; r < 4; ++r)
                    part[(64 * ih + 16 * mt + quad * 4 + r) * PP + jh * 16 + l4] = htp[mt * 4 + r];
            kvt = kvn;
            __syncthreads();   // E

            {
                int d = tid >> 2, kq = tid & 3;
                const float* pp = part + d * PP + kq * 16;
                float v = 0.f;
                #pragma unroll
                for (int i4 = 0; i4 < 4; ++i4) {
                    f32x4 x = *(const f32x4*)(pp + 4 * i4);
                    v += x[0] + x[1] + x[2] + x[3];
                }
                v += __shfl_xor(v, 1, 64);
                v += __shfl_xor(v, 2, 64);
                const u32 seq = (u32)(t + 2);
                const int slot = (int)(seq & SLOTM);
                if (kq == 0)
                    ast64(xq + qid * (SLOTS * 128) + slot * 128 + d,
                          ((u64)seq << 32) | (u64)__builtin_bit_cast(u32, v));
                asm volatile("" ::: "memory");
                #pragma unroll
                for (int mt = 0; mt < 4; ++mt)
                    accF[mt] = (f32x4){0.f, 0.f, 0.f, 0.f};
                {
                    const u16* bp2 = hS + sl * RL + quad * 8;
                    u16x8 bfr[4];
                    #pragma unroll
                    for (int kt = 0; kt < 4; ++kt) bfr[kt] = *(const u16x8*)(bp2 + kt * 32);
                    #pragma unroll
                    for (int mt = 0; mt < 4; ++mt)
                        #pragma unroll
                        for (int kt = 0; kt < 4; ++kt)
                            accF[mt] = mfma16(afr[mt][kt], bfr[kt], accF[mt]);
                }
                if (kq == 0) {
                    u64 pa, pb, pc2;
                    int spins = 0;
                    do {
                        pa  = ald64(xq + qa  * (SLOTS * 128) + slot * 128 + d);
                        pb  = ald64(xq + qb2 * (SLOTS * 128) + slot * 128 + d);
                        pc2 = ald64(xq + qc  * (SLOTS * 128) + slot * 128 + d);
                        if ((u32)(pa >> 32) >= seq && (u32)(pb >> 32) >= seq && (u32)(pc2 >> 32) >= seq) break;
                        if (spins > 64) __builtin_amdgcn_s_sleep(1);
                    } while (++spins < SPIN_CAP);
                    float va = pval(pa), vb = pval(pb), vc = pval(pc2);
                    float v0 = (qid == 0) ? v : (qid == 3) ? va : (qid == 2) ? vb : vc;
                    float v1 = (qid == 1) ? v : (qid == 0) ? va : (qid == 3) ? vb : vc;
                    float v2 = (qid == 2) ? v : (qid == 1) ? va : (qid == 0) ? vb : vc;
                    float v3 = (qid == 3) ? v : (qid == 2) ? va : (qid == 1) ? vb : vc;
                    float vt = ((v0 + v1) + v2) + v3;
                    float hf = (float)(__bf16)vt;
                    htbf[d] = bfu(vt);
                    htbf[128 + d] = bfu(vt - hf);
                    if (qid == 0)
                        astf(jrnF + ((size_t)b * T_SZ + t) * 128 + d, vt);
                }
            }
            if (qid == 0) asm volatile("s_waitcnt vmcnt(0)" ::: "memory");
            __syncthreads();   // TOP
            if (qid == 0 && tid == 0)
                __hip_atomic_store(jflg + b * T_SZ + t, 1,
                                   __ATOMIC_RELAXED, __HIP_MEMORY_SCOPE_AGENT);
        }
    } else {
        // ================= PRODUCER (WT-coalesced weights) =================
        const int p  = role - 4;             // 0..3
        const int o  = tid & 127;
        const int g  = tid >> 7;             // 0..3
        const int t0 = 32 * p;
        const int tend = (t0 + 32 < T_SZ) ? t0 + 32 : T_SZ;
        float* leP   = (float*)smem;                 // [33][128] -> 16896
        float* htP   = (float*)(smem + 16896);       // [128]     -> 17408
        float* part2 = (float*)(smem + 17408);       // [4][128]  -> 19456

        const float b1o = b1[o];
        float wsum = 0.f;
        #pragma unroll 4
        for (int k4 = 64; k4 < 96; ++k4) {
            f32x4 w = *(const f32x4*)(WT + W1T_OFF + (k4 * 128 + o) * 4);
            wsum += w[0] + w[1] + w[2] + w[3];
        }
        // initial lp row = le(t0-1) (or 0 at t0==0)
        if (g == 0) {
            if (t0 == 0) {
                leP[o] = 0.f;
            } else {
                int tt = t0 - 1, idx = b * S_SZ + tt;
                int e = eid[idx], a = atime[idx];
                float av = (float)ansv[idx];
                float acc = b1o;
                #pragma unroll 2
                for (int k4 = 0; k4 < 32; ++k4)
                    acc += dot4(*(const f32x4*)(WT + W1T_OFF + (k4 * 128 + o) * 4),
                                *(const f32x4*)(ex_t + e * DK + 4 * k4));
                #pragma unroll 2
                for (int k4 = 32; k4 < 64; ++k4)
                    acc += dot4(*(const f32x4*)(WT + W1T_OFF + (k4 * 128 + o) * 4),
                                *(const f32x4*)(at_t + a * DK + 4 * k4 - 128));
                leP[o] = acc + av * wsum;
            }
        }
        __syncthreads();

        const float bl0 = blv[o], bg0 = bgv[o], bf0 = bfv[o];

        for (int gi2 = 0; gi2 < 8; ++gi2) {
            int tg = t0 + 4 * gi2;
            if (tg >= tend) break;
            int t = tg + g;
            bool act = (t < tend);
            if (act) {
                // ---- le(t) ----
                int idx = b * S_SZ + t;
                int e = eid[idx], a = atime[idx];
                float av = (float)ansv[idx];
                float acc = b1o;
                #pragma unroll 2
                for (int k4 = 0; k4 < 32; ++k4)
                    acc += dot4(*(const f32x4*)(WT + W1T_OFF + (k4 * 128 + o) * 4),
                                *(const f32x4*)(ex_t + e * DK + 4 * k4));
                #pragma unroll 2
                for (int k4 = 32; k4 < 64; ++k4)
                    acc += dot4(*(const f32x4*)(WT + W1T_OFF + (k4 * 128 + o) * 4),
                                *(const f32x4*)(at_t + a * DK + 4 * k4 - 128));
                leP[(t - t0 + 1) * 128 + o] = acc + av * wsum;
            }
            __syncthreads();
            if (act) {
                // ---- PRE(t) ----
                const float* lp = leP + (t - t0) * 128;
                const float* lc = leP + (t - t0 + 1) * 128;
                const float mP = (t == 0) ? 0.f : 1.f;
                int iv = itime[b * S_SZ + t + 1];
                float al = bl0, ag = bg0;
                #pragma unroll 2
                for (int k4 = 0; k4 < 32; ++k4) {
                    f32x4 w  = *(const f32x4*)(WT + WLT_OFF + (k4 * 128 + o) * 4);
                    f32x4 w2 = *(const f32x4*)(WT + WGT_OFF + (k4 * 128 + o) * 4);
                    f32x4 x  = *(const f32x4*)(lp + 4 * k4);
                    #pragma unroll
                    for (int j = 0; j < 4; ++j) {
                        float xv = x[j] * mP;
                        al += w[j] * xv; ag += w2[j] * xv;
                    }
                }
                #pragma unroll 2
                for (int k4 = 32; k4 < 64; ++k4) {
                    f32x4 w  = *(const f32x4*)(WT + WLT_OFF + (k4 * 128 + o) * 4);
                    f32x4 w2 = *(const f32x4*)(WT + WGT_OFF + (k4 * 128 + o) * 4);
                    f32x4 x  = *(const f32x4*)(it_t + iv * DK + 4 * k4 - 128);
                    #pragma unroll
                    for (int j = 0; j < 4; ++j) {
                        al += w[j] * x[j]; ag += w2[j] * x[j];
                    }
                }
                #pragma unroll 2
                for (int k4 = 64; k4 < 96; ++k4) {
                    f32x4 w  = *(const f32x4*)(WT + WLT_OFF + (k4 * 128 + o) * 4);
                    f32x4 w2 = *(const f32x4*)(WT + WGT_OFF + (k4 * 128 + o) * 4);
                    f32x4 x  = *(const f32x4*)(lc + 4 * k4 - 256);
                    #pragma unroll
                    for (int j = 0; j < 4; ++j) {
                        al += w[j] * x[j]; ag += w2[j] * x[j];
                    }
                }
                float af = bf0;
                #pragma unroll 2
                for (int k4 = 0; k4 < 32; ++k4)
                    af += dot4(*(const f32x4*)(WT + WFT_OFF + ((64 + k4) * 128 + o) * 4),
                               *(const f32x4*)(it_t + iv * DK + 4 * k4));
                size_t idx2 = (size_t)(b * T_SZ + t) * DK + o;
                astf(PRE_l + idx2, al);
                astf(PRE_g + idx2, ag);
                astf(PRE_f + idx2, af);
            }
            asm volatile("s_waitcnt vmcnt(0)" ::: "memory");
            __syncthreads();
            if (tid == 0)
                __hip_atomic_store(flagsP + b * 32 + (tg >> 2), 1,
                                   __ATOMIC_RELAXED, __HIP_MEMORY_SCOPE_AGENT);
        }

        // ---- pred phase: consume write-once journal ----
        f32x4 wp[16];
        #pragma unroll
        for (int k = 0; k < 16; ++k)
            wp[k] = *(const f32x4*)(WT + WPT_OFF + ((16 * g + k) * 128 + o) * 4);
        const float bp_o = bpv[o];
        for (int t = t0; t < tend; ++t) {
            if (g == 0) {
                int sp = 0;
                while (__hip_atomic_load(jflg + b * T_SZ + t,
                                         __ATOMIC_RELAXED, __HIP_MEMORY_SCOPE_AGENT) == 0) {
                    if (sp > 64) __builtin_amdgcn_s_sleep(1);
                    if (++sp > SPIN_CAP) break;
                }
                htP[o] = aldf(jrnF + ((size_t)b * T_SZ + t) * 128 + o);
            }
            __syncthreads();
            int e2 = eid[b * S_SZ + t + 1];
            float acc = 0.f;
            if (g < 2) {
                const float* xr = ex_t + e2 * DK + 64 * g;
                #pragma unroll 4
                for (int k = 0; k < 16; ++k)
                    acc += dot4(wp[k], *(const f32x4*)(xr + 4 * k));
            } else {
                const float* xr = htP + 64 * (g - 2);
                #pragma unroll 4
                for (int k = 0; k < 16; ++k)
                    acc += dot4(wp[k], *(const f32x4*)(xr + 4 * k));
            }
            part2[g * 128 + o] = acc;
            __syncthreads();
            if (g == 0) {
                float s = ((part2[o] + part2[128 + o]) + part2[256 + o]) + part2[384 + o] + bp_o;
                out[(size_t)(b * T_SZ + t) * DK + o] = sigm(s);
            }
            __syncthreads();
        }
    }
}

extern "C" void kernel_launch(void* const* d_in, const int* in_sizes, int n_in,
                              void* d_out, int out_size, void* d_ws, size_t ws_size,
                              hipStream_t stream) {
    const int* eid     = (const int*)d_in[0];
    const int* atime   = (const int*)d_in[1];
    const int* itime   = (const int*)d_in[2];
    const int* ansv    = (const int*)d_in[3];
    const float* qmat  = (const float*)d_in[4];
    const float* ex_t  = (const float*)d_in[5];
    const float* at_t  = (const float*)d_in[6];
    const float* it_t  = (const float*)d_in[7];
    const float* W1    = (const float*)d_in[8];
    const float* b1    = (const float*)d_in[9];
    const float* Wl    = (const float*)d_in[10];
    const float* blv   = (const float*)d_in[11];
    const float* Wg    = (const float*)d_in[12];
    const float* bgv   = (const float*)d_in[13];
    const float* Wf    = (const float*)d_in[14];
    const float* bfv   = (const float*)d_in[15];
    const float* Wp    = (const float*)d_in[16];
    const float* bpv   = (const float*)d_in[17];
    const float* h0    = (const float*)d_in[18];
    float* out = (float*)d_out;

    const size_t SZ = (size_t)B_SZ * T_SZ * DK;   // 520192 floats
    float* wsf   = (float*)d_ws;
    // region [0, SZ): xbuf (512 KiB) + flags + WT (1 MiB)
    u64*   xbuf   = (u64*)wsf;                    // 65536 u64 = 131072 f32 slots
    int*   flagsP = (int*)(wsf + 131072);         // 32*32 ints
    int*   jflg   = flagsP + 1024;                // 32*127 ints
    float* WT     = wsf + 139264;                 // 262144 floats (ends 401408)
    float* PRE_l = wsf + SZ;
    float* PRE_g = wsf + 2 * SZ;
    float* PRE_f = wsf + 3 * SZ;
    float* jrnF  = wsf + 4 * SZ;                  // 32*127*128 f32 (write-once)

    hipFuncSetAttribute((const void*)k_mono,
                        hipFuncAttributeMaxDynamicSharedMemorySize, 86016);

    // re-arm comm state each replay (packets + PRE flags + journal flags)
    hipMemsetAsync(wsf, 0, 524288 + 1024 * 4 + 32 * T_SZ * 4, stream);
    k_prep<<<dim3(WT_TOTAL / 256), 256, 0, stream>>>(W1, Wl, Wg, Wf, Wp, WT);
    k_mono<<<dim3(B_SZ, 8), 512, 86016, stream>>>(
        eid, atime, itime, ansv, qmat, ex_t, at_t, it_t, WT, b1,
        Wl, blv, Wg, bgv, Wf, bfv, bpv, h0,
        PRE_l, PRE_g, PRE_f, out, xbuf, jrnF, jflg, flagsP);
}

// Round 12
// 634.812 us; speedup vs baseline: 1.0718x; 1.0718x over previous
//
#include <hip/hip_runtime.h>

typedef unsigned int u32;
typedef unsigned short u16;
typedef unsigned long long u64;
typedef u16 u16x8 __attribute__((ext_vector_type(8)));
typedef u16 u16x4 __attribute__((ext_vector_type(4)));
typedef __bf16 bf16x8 __attribute__((ext_vector_type(8)));
typedef __bf16 bf16x4v __attribute__((ext_vector_type(4)));
typedef float f32x4 __attribute__((ext_vector_type(4)));
typedef float f32x2 __attribute__((ext_vector_type(2)));

#define B_SZ 32
#define S_SZ 128
#define T_SZ 127
#define DK 128
#define SKILL 256
#define SQTR 64    /* skills per block (4-way split) */
#define RL 136     /* hS row pitch (u16): 128 + 8 pad */
#define PP 68      /* part row pitch (f32): 64 + 4 pad */
#define NPAIR 8    /* (b,t) pairs per aux block; 4064 = 508*8 */
#define SPIN_CAP (1 << 18)

__device__ __forceinline__ u16x4 cvt4(f32x4 v) {
    return __builtin_bit_cast(u16x4, __builtin_convertvector(v, bf16x4v));
}
__device__ __forceinline__ u16x8 cvt8(f32x4 a, f32x4 b) {
    u16x4 x = cvt4(a), y = cvt4(b);
    u16x8 r;
    r[0]=x[0]; r[1]=x[1]; r[2]=x[2]; r[3]=x[3];
    r[4]=y[0]; r[5]=y[1]; r[6]=y[2]; r[7]=y[3];
    return r;
}
__device__ __forceinline__ u16 bfu(float x) {
    return __builtin_bit_cast(u16, (__bf16)x);
}
__device__ __forceinline__ float sigm(float x) {
    float e = __builtin_amdgcn_exp2f(-1.44269504f * x);
    return __builtin_amdgcn_rcpf(1.f + e);
}
__device__ __forceinline__ float tanh_f(float x) {
    float e = __builtin_amdgcn_exp2f(-2.88539008f * x);
    return 2.f * __builtin_amdgcn_rcpf(1.f + e) - 1.f;
}
__device__ __forceinline__ f32x4 mfma16(u16x8 a, u16x8 bb, f32x4 c) {
    return __builtin_amdgcn_mfma_f32_16x16x32_bf16(
        __builtin_bit_cast(bf16x8, a), __builtin_bit_cast(bf16x8, bb), c, 0, 0, 0);
}
__device__ __forceinline__ float pval(u64 p) {
    return __builtin_bit_cast(float, (u32)p);
}
__device__ __forceinline__ float dot4(f32x4 w, f32x4 x) {
    return w[0] * x[0] + w[1] * x[1] + w[2] * x[2] + w[3] * x[3];
}

// ---------------------------------------------------------------------------
// Kernel A: le = W1 @ [ex | at | ans] + b1. (R9 proven)
// ---------------------------------------------------------------------------
__global__ __launch_bounds__(128, 2) void k_le(
    const int* __restrict__ eid, const int* __restrict__ atime,
    const int* __restrict__ ansv, const float* __restrict__ ex_t,
    const float* __restrict__ at_t, const float* __restrict__ W1,
    const float* __restrict__ b1, float* __restrict__ le_ws)
{
    const int o = threadIdx.x;
    const int p0 = blockIdx.x * NPAIR;
    int eP[NPAIR], aP[NPAIR];
    float avP[NPAIR];
    #pragma unroll
    for (int i = 0; i < NPAIR; ++i) {
        int p = p0 + i, b = p / T_SZ, t = p - b * T_SZ;
        int idx = b * S_SZ + t;
        eP[i] = eid[idx];
        aP[i] = atime[idx];
        avP[i] = (float)ansv[idx];
    }
    const float* wr = W1 + o * 384;
    const float bias = b1[o];
    float acc[NPAIR];
    #pragma unroll
    for (int i = 0; i < NPAIR; ++i) acc[i] = bias;
    #pragma unroll 2
    for (int k4 = 0; k4 < 32; ++k4) {
        f32x4 w = *(const f32x4*)(wr + 4 * k4);
        #pragma unroll
        for (int i = 0; i < NPAIR; ++i) {
            f32x4 x = *(const f32x4*)(ex_t + eP[i] * DK + 4 * k4);
            acc[i] += dot4(w, x);
        }
    }
    #pragma unroll 2
    for (int k4 = 32; k4 < 64; ++k4) {
        f32x4 w = *(const f32x4*)(wr + 4 * k4);
        #pragma unroll
        for (int i = 0; i < NPAIR; ++i) {
            f32x4 x = *(const f32x4*)(at_t + aP[i] * DK + 4 * k4 - 128);
            acc[i] += dot4(w, x);
        }
    }
    float wsum = 0.f;
    #pragma unroll 4
    for (int k4 = 64; k4 < 96; ++k4) {
        f32x4 w = *(const f32x4*)(wr + 4 * k4);
        wsum += w[0] + w[1] + w[2] + w[3];
    }
    #pragma unroll
    for (int i = 0; i < NPAIR; ++i)
        le_ws[(p0 + i) * DK + o] = acc[i] + avP[i] * wsum;
}

// ---------------------------------------------------------------------------
// Kernel B: gate pre-activations. (R9 proven)
// ---------------------------------------------------------------------------
__global__ __launch_bounds__(128, 2) void k_pre(
    const int* __restrict__ itime, const float* __restrict__ it_t,
    const float* __restrict__ Wl, const float* __restrict__ blv,
    const float* __restrict__ Wg, const float* __restrict__ bgv,
    const float* __restrict__ Wf, const float* __restrict__ bfv,
    const float* __restrict__ le_ws,
    float* __restrict__ PRE_l, float* __restrict__ PRE_g, float* __restrict__ PRE_f)
{
    const int o = threadIdx.x;
    const int p0 = blockIdx.x * NPAIR;
    int ivP[NPAIR], lpOff[NPAIR];
    float mP[NPAIR];
    #pragma unroll
    for (int i = 0; i < NPAIR; ++i) {
        int p = p0 + i, b = p / T_SZ, t = p - b * T_SZ;
        ivP[i] = itime[b * S_SZ + t + 1];
        mP[i] = (t == 0) ? 0.f : 1.f;
        lpOff[i] = ((t == 0) ? p : p - 1) * DK;
    }
    const float* wl = Wl + o * 512;
    const float* wg = Wg + o * 512;
    const float bl0 = blv[o], bg0 = bgv[o];
    float al[NPAIR], ag[NPAIR];
    #pragma unroll
    for (int i = 0; i < NPAIR; ++i) { al[i] = bl0; ag[i] = bg0; }
    #pragma unroll 2
    for (int k4 = 0; k4 < 32; ++k4) {
        f32x4 w  = *(const f32x4*)(wl + 4 * k4);
        f32x4 w2 = *(const f32x4*)(wg + 4 * k4);
        #pragma unroll
        for (int i = 0; i < NPAIR; ++i) {
            f32x4 x = *(const f32x4*)(le_ws + lpOff[i] + 4 * k4);
            #pragma unroll
            for (int j = 0; j < 4; ++j) {
                float xv = x[j] * mP[i];
                al[i] += w[j] * xv;
                ag[i] += w2[j] * xv;
            }
        }
    }
    #pragma unroll 2
    for (int k4 = 32; k4 < 64; ++k4) {
        f32x4 w  = *(const f32x4*)(wl + 4 * k4);
        f32x4 w2 = *(const f32x4*)(wg + 4 * k4);
        #pragma unroll
        for (int i = 0; i < NPAIR; ++i) {
            f32x4 x = *(const f32x4*)(it_t + ivP[i] * DK + 4 * k4 - 128);
            #pragma unroll
            for (int j = 0; j < 4; ++j) {
                al[i] += w[j] * x[j];
                ag[i] += w2[j] * x[j];
            }
        }
    }
    #pragma unroll 2
    for (int k4 = 64; k4 < 96; ++k4) {
        f32x4 w  = *(const f32x4*)(wl + 4 * k4);
        f32x4 w2 = *(const f32x4*)(wg + 4 * k4);
        #pragma unroll
        for (int i = 0; i < NPAIR; ++i) {
            f32x4 x = *(const f32x4*)(le_ws + (p0 + i) * DK + 4 * k4 - 256);
            #pragma unroll
            for (int j = 0; j < 4; ++j) {
                al[i] += w[j] * x[j];
                ag[i] += w2[j] * x[j];
            }
        }
    }
    const float bf0 = bfv[o];
    float af[NPAIR];
    #pragma unroll
    for (int i = 0; i < NPAIR; ++i) af[i] = bf0;
    const float* wf = Wf + o * 384 + 256;
    #pragma unroll 2
    for (int k4 = 0; k4 < 32; ++k4) {
        f32x4 w = *(const f32x4*)(wf + 4 * k4);
        #pragma unroll
        for (int i = 0; i < NPAIR; ++i) {
            f32x4 x = *(const f32x4*)(it_t + ivP[i] * DK + 4 * k4);
            af[i] += dot4(w, x);
        }
    }
    #pragma unroll
    for (int i = 0; i < NPAIR; ++i) {
        size_t idx = (size_t)(p0 + i) * DK + o;
        PRE_l[idx] = al[i];
        PRE_g[idx] = ag[i];
        PRE_f[idx] = af[i];
    }
}

// ---------------------------------------------------------------------------
// Kernel C: sequential scan, 4-way skill-split, 8-byte packet exchange,
// 1024 THREADS (16 waves, 4/SIMD): every per-step phase spreads over 2x
// the waves of the R5 structure. Wave w2: z M-tile w2; Zf d-tile (w2&7) x
// 2 skill-tiles {2(w2>>3), +1}; c on waves 0-7. MFMA per-output
// accumulation order unchanged vs R5 (bit-identical z/c/Zf).
// ---------------------------------------------------------------------------
__global__ __launch_bounds__(1024, 1) void k_main(
    const int* __restrict__ eid, const float* __restrict__ qmat,
    const float* __restrict__ Wl, const float* __restrict__ Wg,
    const float* __restrict__ Wf, const float* __restrict__ h0,
    const float* __restrict__ PRE_l, const float* __restrict__ PRE_g,
    const float* __restrict__ PRE_f, float* __restrict__ ht_ws,
    u64* __restrict__ xbuf)
{
    extern __shared__ char smem[];
    u16*   hS   = (u16*)smem;                    // 64*136*2  = 17408
    float* part = (float*)(smem + 17408);        // 128*68*4  -> 52224
    u16*   htbf = (u16*)(smem + 52224);          // hi/lo -> 52736
    u16*   LGb  = (u16*)(smem + 52736);          // hi/lo -> 53248
    float* LGf  = (float*)(smem + 53248);        // -> 53760
    float* cS   = (float*)(smem + 53760);        // -> 54272

    const int b    = blockIdx.x;
    const int qid  = blockIdx.y;
    const int tid  = threadIdx.x;
    const int w2   = tid >> 6;       // 0..15
    const int lane = tid & 63;
    const int quad = lane >> 4;
    const int l4   = lane & 15;
    const int mt   = w2 & 7;         // d-tile (Zf/update/c)
    const int np   = w2 >> 3;        // skill-pair group

    u64* xq = xbuf + (size_t)b * 1024;
    const int qa = (qid + 1) & 3, qb2 = (qid + 2) & 3, qc = (qid + 3) & 3;

    // ---- persistent A-frags ----
    u16x8 afr[4];   // Zf: A rows m = 16*mt + l4
    #pragma unroll
    for (int kt = 0; kt < 4; ++kt) {
        const float* p = Wf + (16 * mt + l4) * 384 + 32 * kt + quad * 8;
        afr[kt] = cvt8(*(const f32x4*)p, *(const f32x4*)(p + 4));
    }
    u16x8 azf[4];   // z: rho = 16*w2 + l4 -> d = 8*w2 + (l4>>1), lg = l4&1
    #pragma unroll
    for (int kt = 0; kt < 4; ++kt) {
        int d = 8 * w2 + (l4 >> 1);
        const float* base = (l4 & 1) ? Wg : Wl;
        const float* p = base + d * 512 + 384 + 32 * kt + quad * 8;
        azf[kt] = cvt8(*(const f32x4*)p, *(const f32x4*)(p + 4));
    }
    u16x8 acf[4];   // c: m = 16*(w2&7)+l4 (used by waves 0-7 only)
    #pragma unroll
    for (int kt = 0; kt < 4; ++kt) {
        const float* p = Wf + (16 * mt + l4) * 384 + 128 + 32 * kt + quad * 8;
        acf[kt] = cvt8(*(const f32x4*)p, *(const f32x4*)(p + 4));
    }

    // ---- owned cells: skills s0,s1; d-range d0..d0+3 ----
    const int s0 = 32 * np + l4;         // 16*(2np)+l4
    const int s1 = s0 + 16;
    const int d0 = 16 * mt + 4 * quad;

    f32x4 hreg[2];
    {
        f32x4 hv = *(const f32x4*)(h0 + (SQTR * qid + s0) * DK + d0);
        hreg[0] = hv;
        *(u16x4*)(hS + s0 * RL + d0) = cvt4(hv);
        hv = *(const f32x4*)(h0 + (SQTR * qid + s1) * DK + d0);
        hreg[1] = hv;
        *(u16x4*)(hS + s1 * RL + d0) = cvt4(hv);
    }

    float kvt[2];
    {
        int e0 = eid[b * S_SZ];
        kvt[0] = qmat[e0 * SKILL + SQTR * qid + s0];
        kvt[1] = qmat[e0 * SKILL + SQTR * qid + s1];
    }

    f32x4 accF[2];

    // ---- prologue: h~0 exchange + Zf(0) ----
    {
        #pragma unroll
        for (int i = 0; i < 2; ++i) {
            int s = i ? s1 : s0;
            #pragma unroll
            for (int r = 0; r < 4; ++r)
                part[(d0 + r) * PP + s] = kvt[i] * hreg[i][r];
        }
        __syncthreads();
        int d = tid >> 3, kq = tid & 7;
        const float* pp = part + d * PP + kq * 8;
        f32x4 x0 = *(const f32x4*)pp;
        f32x4 x1 = *(const f32x4*)(pp + 4);
        float v = (x0[0] + x0[1] + x0[2] + x0[3]) + (x1[0] + x1[1] + x1[2] + x1[3]);
        v += __shfl_xor(v, 1, 64);
        v += __shfl_xor(v, 2, 64);
        v += __shfl_xor(v, 4, 64);
        if (kq == 0) {
            u64 pkt = ((u64)1u << 32) | (u64)__builtin_bit_cast(u32, v);
            __hip_atomic_store(xq + qid * 256 + 128 + d, pkt,
                               __ATOMIC_RELAXED, __HIP_MEMORY_SCOPE_AGENT);
        }
        asm volatile("" ::: "memory");
        accF[0] = (f32x4){0.f, 0.f, 0.f, 0.f};
        accF[1] = (f32x4){0.f, 0.f, 0.f, 0.f};
        #pragma unroll
        for (int i = 0; i < 2; ++i) {
            const u16* bp2 = hS + (i ? s1 : s0) * RL + quad * 8;
            u16x8 bfr[4];
            #pragma unroll
            for (int kt = 0; kt < 4; ++kt) bfr[kt] = *(const u16x8*)(bp2 + kt * 32);
            #pragma unroll
            for (int kt = 0; kt < 4; ++kt)
                accF[i] = mfma16(afr[kt], bfr[kt], accF[i]);
        }
        if (kq == 0) {
            u64 pa, pb, pc2;
            int spins = 0;
            do {
                pa  = __hip_atomic_load(xq + qa * 256 + 128 + d, __ATOMIC_RELAXED, __HIP_MEMORY_SCOPE_AGENT);
                pb  = __hip_atomic_load(xq + qb2 * 256 + 128 + d, __ATOMIC_RELAXED, __HIP_MEMORY_SCOPE_AGENT);
                pc2 = __hip_atomic_load(xq + qc * 256 + 128 + d, __ATOMIC_RELAXED, __HIP_MEMORY_SCOPE_AGENT);
                if ((u32)(pa >> 32) >= 1u && (u32)(pb >> 32) >= 1u && (u32)(pc2 >> 32) >= 1u) break;
                if (spins > 64) __builtin_amdgcn_s_sleep(1);
            } while (++spins < SPIN_CAP);
            float va = pval(pa), vb = pval(pb), vc = pval(pc2);
            float v0 = (qid == 0) ? v : (qid == 3) ? va : (qid == 2) ? vb : vc;
            float v1 = (qid == 1) ? v : (qid == 0) ? va : (qid == 3) ? vb : vc;
            float v2 = (qid == 2) ? v : (qid == 1) ? va : (qid == 0) ? vb : vc;
            float v3 = (qid == 3) ? v : (qid == 2) ? va : (qid == 1) ? vb : vc;
            float vt = ((v0 + v1) + v2) + v3;
            float hf = (float)(__bf16)vt;
            htbf[d] = bfu(vt);
            htbf[128 + d] = bfu(vt - hf);
        }
        __syncthreads();
    }

    for (int t = 0; t < T_SZ; ++t) {
        const size_t tb = (size_t)(b * T_SZ + t) * DK;
        float kvn[2];
        {
            int en = eid[b * S_SZ + t + 1];
            kvn[0] = qmat[en * SKILL + SQTR * qid + s0];
            kvn[1] = qmat[en * SKILL + SQTR * qid + s1];
        }
        const int dz = 8 * w2 + 2 * quad;     // z-output d-pair base
        f32x2 pl = *(const f32x2*)(PRE_l + tb + dz);
        f32x2 pg = *(const f32x2*)(PRE_g + tb + dz);
        f32x4 pf;
        if (w2 < 8) pf = *(const f32x4*)(PRE_f + tb + 16 * w2 + 4 * quad);

        // ---- z-MFMA: one 16-row M-tile per wave ----
        f32x4 accZ = (f32x4){0.f, 0.f, 0.f, 0.f};
        #pragma unroll
        for (int kt = 0; kt < 4; ++kt) {
            u16x8 bh = *(const u16x8*)(htbf + 32 * kt + quad * 8);
            u16x8 bl = *(const u16x8*)(htbf + 128 + 32 * kt + quad * 8);
            accZ = mfma16(azf[kt], bh, accZ);
            accZ = mfma16(azf[kt], bl, accZ);
        }
        {
            u32 hpack = 0, lpack = 0;
            f32x2 fpack;
            #pragma unroll
            for (int rp = 0; rp < 2; ++rp) {
                float zl = accZ[2 * rp] + pl[rp];
                float zg = accZ[2 * rp + 1] + pg[rp];
                float LGv = sigm(zg) * (tanh_f(zl) + 1.f) * 0.5f;
                float hif = (float)(__bf16)LGv;
                hpack |= ((u32)bfu(LGv)) << (16 * rp);
                lpack |= ((u32)bfu(LGv - hif)) << (16 * rp);
                fpack[rp] = LGv;
            }
            if (l4 == 0) {
                *(u32*)(LGb + dz) = hpack;
                *(u32*)(LGb + 128 + dz) = lpack;
                *(f32x2*)(LGf + dz) = fpack;
            }
        }
        __syncthreads();   // B: LG ready

        // ---- c-MFMA on waves 0-7 ----
        if (w2 < 8) {
            f32x4 accC = (f32x4){0.f, 0.f, 0.f, 0.f};
            #pragma unroll
            for (int kt = 0; kt < 4; ++kt) {
                u16x8 bh = *(const u16x8*)(LGb + 32 * kt + quad * 8);
                u16x8 bl = *(const u16x8*)(LGb + 128 + 32 * kt + quad * 8);
                accC = mfma16(acf[kt], bh, accC);
                accC = mfma16(acf[kt], bl, accC);
            }
            accC += pf;
            if (l4 == 0) *(f32x4*)(cS + 16 * w2 + 4 * quad) = accC;
        }
        __syncthreads();   // C: c ready

        // ---- update (2 skills x 4 d per thread) ----
        {
            f32x4 lg = *(const f32x4*)(LGf + d0);
            f32x4 cc = *(const f32x4*)(cS + d0);
            #pragma unroll
            for (int i = 0; i < 2; ++i) {
                int s = i ? s1 : s0;
                f32x4 hv;
                #pragma unroll
                for (int r = 0; r < 4; ++r) {
                    float f = sigm(accF[i][r] + cc[r]);
                    float hn = kvt[i] * lg[r] + f * hreg[i][r];
                    hreg[i][r] = hn;
                    hv[r] = hn;
                    part[(d0 + r) * PP + s] = kvn[i] * hn;
                }
                *(u16x4*)(hS + s * RL + d0) = cvt4(hv);
            }
            kvt[0] = kvn[0];
            kvt[1] = kvn[1];
        }
        __syncthreads();   // E: partials + hS(t+1) ready

        // ---- reduce -> quarter-partial; publish; Zf(t+1) in gap; poll ----
        {
            int d = tid >> 3, kq = tid & 7;
            const float* pp = part + d * PP + kq * 8;
            f32x4 x0 = *(const f32x4*)pp;
            f32x4 x1 = *(const f32x4*)(pp + 4);
            float v = (x0[0] + x0[1] + x0[2] + x0[3]) + (x1[0] + x1[1] + x1[2] + x1[3]);
            v += __shfl_xor(v, 1, 64);
            v += __shfl_xor(v, 2, 64);
            v += __shfl_xor(v, 4, 64);
            const int slot = t & 1;            // seq = t+2
            const u32 seq = (u32)(t + 2);
            if (kq == 0) {
                u64 pkt = ((u64)seq << 32) | (u64)__builtin_bit_cast(u32, v);
                __hip_atomic_store(xq + qid * 256 + slot * 128 + d, pkt,
                                   __ATOMIC_RELAXED, __HIP_MEMORY_SCOPE_AGENT);
            }
            asm volatile("" ::: "memory");
            accF[0] = (f32x4){0.f, 0.f, 0.f, 0.f};
            accF[1] = (f32x4){0.f, 0.f, 0.f, 0.f};
            #pragma unroll
            for (int i = 0; i < 2; ++i) {
                const u16* bp2 = hS + (i ? s1 : s0) * RL + quad * 8;
                u16x8 bfr[4];
                #pragma unroll
                for (int kt = 0; kt < 4; ++kt) bfr[kt] = *(const u16x8*)(bp2 + kt * 32);
                #pragma unroll
                for (int kt = 0; kt < 4; ++kt)
                    accF[i] = mfma16(afr[kt], bfr[kt], accF[i]);
            }
            if (kq == 0) {
                u64 pa, pb, pc2;
                int spins = 0;
                do {
                    pa  = __hip_atomic_load(xq + qa * 256 + slot * 128 + d, __ATOMIC_RELAXED, __HIP_MEMORY_SCOPE_AGENT);
                    pb  = __hip_atomic_load(xq + qb2 * 256 + slot * 128 + d, __ATOMIC_RELAXED, __HIP_MEMORY_SCOPE_AGENT);
                    pc2 = __hip_atomic_load(xq + qc * 256 + slot * 128 + d, __ATOMIC_RELAXED, __HIP_MEMORY_SCOPE_AGENT);
                    if ((u32)(pa >> 32) >= seq && (u32)(pb >> 32) >= seq && (u32)(pc2 >> 32) >= seq) break;
                    if (spins > 64) __builtin_amdgcn_s_sleep(1);
                } while (++spins < SPIN_CAP);
                float va = pval(pa), vb = pval(pb), vc = pval(pc2);
                float v0 = (qid == 0) ? v : (qid == 3) ? va : (qid == 2) ? vb : vc;
                float v1 = (qid == 1) ? v : (qid == 0) ? va : (qid == 3) ? vb : vc;
                float v2 = (qid == 2) ? v : (qid == 1) ? va : (qid == 0) ? vb : vc;
                float v3 = (qid == 3) ? v : (qid == 2) ? va : (qid == 1) ? vb : vc;
                float vt = ((v0 + v1) + v2) + v3;
                float hf = (float)(__bf16)vt;
                htbf[d] = bfu(vt);
                htbf[128 + d] = bfu(vt - hf);
                if (qid == 0) ht_ws[tb + d] = vt;
            }
        }
        __syncthreads();   // TOP: h~ ready
    }
}

// ---------------------------------------------------------------------------
// Kernel D: pred. (R9 proven)
// ---------------------------------------------------------------------------
__global__ __launch_bounds__(128, 2) void k_pred(
    const int* __restrict__ eid, const float* __restrict__ ex_t,
    const float* __restrict__ Wp, const float* __restrict__ bpv,
    const float* __restrict__ ht_ws, float* __restrict__ out)
{
    const int o = threadIdx.x;
    const int p0 = blockIdx.x * NPAIR;
    int eP[NPAIR];
    #pragma unroll
    for (int i = 0; i < NPAIR; ++i) {
        int p = p0 + i, b = p / T_SZ, t = p - b * T_SZ;
        eP[i] = eid[b * S_SZ + t + 1];
    }
    const float* wr = Wp + o * 256;
    const float bias = bpv[o];
    float acc[NPAIR];
    #pragma unroll
    for (int i = 0; i < NPAIR; ++i) acc[i] = bias;
    #pragma unroll 2
    for (int k4 = 0; k4 < 32; ++k4) {
        f32x4 w = *(const f32x4*)(wr + 4 * k4);
        #pragma unroll
        for (int i = 0; i < NPAIR; ++i) {
            f32x4 x = *(const f32x4*)(ex_t + eP[i] * DK + 4 * k4);
            acc[i] += dot4(w, x);
        }
    }
    #pragma unroll 2
    for (int k4 = 32; k4 < 64; ++k4) {
        f32x4 w = *(const f32x4*)(wr + 4 * k4);
        #pragma unroll
        for (int i = 0; i < NPAIR; ++i) {
            f32x4 x = *(const f32x4*)(ht_ws + (size_t)(p0 + i) * DK + 4 * k4 - 128);
            acc[i] += dot4(w, x);
        }
    }
    #pragma unroll
    for (int i = 0; i < NPAIR; ++i)
        out[(size_t)(p0 + i) * DK + o] = sigm(acc[i]);
}

extern "C" void kernel_launch(void* const* d_in, const int* in_sizes, int n_in,
                              void* d_out, int out_size, void* d_ws, size_t ws_size,
                              hipStream_t stream) {
    const int* eid     = (const int*)d_in[0];
    const int* atime   = (const int*)d_in[1];
    const int* itime   = (const int*)d_in[2];
    const int* ansv    = (const int*)d_in[3];
    const float* qmat  = (const float*)d_in[4];
    const float* ex_t  = (const float*)d_in[5];
    const float* at_t  = (const float*)d_in[6];
    const float* it_t  = (const float*)d_in[7];
    const float* W1    = (const float*)d_in[8];
    const float* b1    = (const float*)d_in[9];
    const float* Wl    = (const float*)d_in[10];
    const float* blv   = (const float*)d_in[11];
    const float* Wg    = (const float*)d_in[12];
    const float* bgv   = (const float*)d_in[13];
    const float* Wf    = (const float*)d_in[14];
    const float* bfv   = (const float*)d_in[15];
    const float* Wp    = (const float*)d_in[16];
    const float* bpv   = (const float*)d_in[17];
    const float* h0    = (const float*)d_in[18];
    float* out = (float*)d_out;

    const size_t SZ = (size_t)B_SZ * T_SZ * DK;
    float* wsf   = (float*)d_ws;
    float* le_ws = wsf;
    float* PRE_l = wsf + SZ;
    float* PRE_g = wsf + 2 * SZ;
    float* PRE_f = wsf + 3 * SZ;
    float* ht_ws = wsf + 4 * SZ;
    // le_ws is dead after k_pre -> reuse its head for the packet buffer.
    u64* xbuf = (u64*)le_ws;                   // 32*4*2*128 u64 = 256 KiB

    hipFuncSetAttribute((const void*)k_main,
                        hipFuncAttributeMaxDynamicSharedMemorySize, 54272);

    dim3 gaux(508);
    k_le  <<<gaux, 128, 0, stream>>>(eid, atime, ansv, ex_t, at_t, W1, b1, le_ws);
    k_pre <<<gaux, 128, 0, stream>>>(itime, it_t, Wl, blv, Wg, bgv, Wf, bfv,
                                     le_ws, PRE_l, PRE_g, PRE_f);
    // re-arm packet buffer each replay (stale seq from prior replay otherwise)
    hipMemsetAsync(xbuf, 0, (size_t)B_SZ * 1024 * sizeof(u64), stream);
    k_main<<<dim3(B_SZ, 4), 1024, 54272, stream>>>(eid, qmat, Wl, Wg, Wf, h0,
                                                   PRE_l, PRE_g, PRE_f, ht_ws,
                                                   xbuf);
    k_pred<<<gaux, 128, 0, stream>>>(eid, ex_t, Wp, bpv, ht_ws, out);
}

// Round 14
// 595.102 us; speedup vs baseline: 1.1433x; 1.0667x over previous
//
#include <hip/hip_runtime.h>

typedef unsigned int u32;
typedef unsigned short u16;
typedef unsigned long long u64;
typedef u16 u16x8 __attribute__((ext_vector_type(8)));
typedef u16 u16x4 __attribute__((ext_vector_type(4)));
typedef __bf16 bf16x8 __attribute__((ext_vector_type(8)));
typedef __bf16 bf16x4v __attribute__((ext_vector_type(4)));
typedef float f32x4 __attribute__((ext_vector_type(4)));
typedef float f32x2 __attribute__((ext_vector_type(2)));

#define B_SZ 32
#define S_SZ 128
#define T_SZ 127
#define DK 128
#define SKILL 256
#define SQTR 64    /* skills per block (4-way split) */
#define RL 136     /* hS row pitch (u16): 128 + 8 pad */
#define PP 68      /* part row pitch (f32): 64 + 4 pad */
#define NPAIR 8    /* (b,t) pairs per aux block; 4064 = 508*8 */
#define SPIN_CAP (1 << 18)

__device__ __forceinline__ u16x4 cvt4(f32x4 v) {
    return __builtin_bit_cast(u16x4, __builtin_convertvector(v, bf16x4v));
}
__device__ __forceinline__ u16x8 cvt8(f32x4 a, f32x4 b) {
    u16x4 x = cvt4(a), y = cvt4(b);
    u16x8 r;
    r[0]=x[0]; r[1]=x[1]; r[2]=x[2]; r[3]=x[3];
    r[4]=y[0]; r[5]=y[1]; r[6]=y[2]; r[7]=y[3];
    return r;
}
__device__ __forceinline__ u16 bfu(float x) {
    return __builtin_bit_cast(u16, (__bf16)x);
}
__device__ __forceinline__ float sigm(float x) {
    float e = __builtin_amdgcn_exp2f(-1.44269504f * x);
    return __builtin_amdgcn_rcpf(1.f + e);
}
__device__ __forceinline__ float tanh_f(float x) {
    float e = __builtin_amdgcn_exp2f(-2.88539008f * x);
    return 2.f * __builtin_amdgcn_rcpf(1.f + e) - 1.f;
}
__device__ __forceinline__ f32x4 mfma16(u16x8 a, u16x8 bb, f32x4 c) {
    return __builtin_amdgcn_mfma_f32_16x16x32_bf16(
        __builtin_bit_cast(bf16x8, a), __builtin_bit_cast(bf16x8, bb), c, 0, 0, 0);
}
__device__ __forceinline__ float pval(u64 p) {
    return __builtin_bit_cast(float, (u32)p);
}

// ---------------------------------------------------------------------------
// Kernel A: le = W1 @ [ex | at | ans] + b1. No LDS staging: x rows are
// wave-uniform (pair base via readfirstlane) -> scalar-pipe loads.
// ---------------------------------------------------------------------------
__global__ __launch_bounds__(256) void k_le(
    const int* __restrict__ eid, const int* __restrict__ atime,
    const int* __restrict__ ansv, const float* __restrict__ ex_t,
    const float* __restrict__ at_t, const float* __restrict__ W1,
    const float* __restrict__ b1, float* __restrict__ le_ws)
{
    const int tid = threadIdx.x;
    const int o = tid & 127;
    const int gi = __builtin_amdgcn_readfirstlane(tid >> 7);
    const int p0 = blockIdx.x * NPAIR + gi * 4;
    int eP[4], aP[4];
    float avP[4];
    #pragma unroll
    for (int i = 0; i < 4; ++i) {
        int p = p0 + i, b = p / T_SZ, t = p - b * T_SZ;
        int idx = b * S_SZ + t;
        eP[i] = eid[idx];
        aP[i] = atime[idx];
        avP[i] = (float)ansv[idx];
    }
    const float* wr = W1 + o * 384;
    const float bias = b1[o];
    float acc[4] = {bias, bias, bias, bias};
    #pragma unroll 4
    for (int k4 = 0; k4 < 32; ++k4) {
        f32x4 w = *(const f32x4*)(wr + 4 * k4);
        #pragma unroll
        for (int i = 0; i < 4; ++i) {
            f32x4 x = *(const f32x4*)(ex_t + eP[i] * DK + 4 * k4);
            acc[i] += w[0] * x[0] + w[1] * x[1] + w[2] * x[2] + w[3] * x[3];
        }
    }
    #pragma unroll 4
    for (int k4 = 32; k4 < 64; ++k4) {
        f32x4 w = *(const f32x4*)(wr + 4 * k4);
        #pragma unroll
        for (int i = 0; i < 4; ++i) {
            f32x4 x = *(const f32x4*)(at_t + aP[i] * DK + 4 * k4 - 128);
            acc[i] += w[0] * x[0] + w[1] * x[1] + w[2] * x[2] + w[3] * x[3];
        }
    }
    float wsum = 0.f;
    #pragma unroll 4
    for (int k4 = 64; k4 < 96; ++k4) {
        f32x4 w = *(const f32x4*)(wr + 4 * k4);
        wsum += w[0] + w[1] + w[2] + w[3];
    }
    #pragma unroll
    for (int i = 0; i < 4; ++i)
        le_ws[(p0 + i) * DK + o] = acc[i] + avP[i] * wsum;
}

// ---------------------------------------------------------------------------
// Kernel B: gate pre-activations. No LDS staging; x rows wave-uniform.
// t==0 lp handled by exact mask-multiply (w*(0*x) adds 0.0 -> bit-identical).
// ---------------------------------------------------------------------------
__global__ __launch_bounds__(256) void k_pre(
    const int* __restrict__ itime, const float* __restrict__ it_t,
    const float* __restrict__ Wl, const float* __restrict__ blv,
    const float* __restrict__ Wg, const float* __restrict__ bgv,
    const float* __restrict__ Wf, const float* __restrict__ bfv,
    const float* __restrict__ le_ws,
    float* __restrict__ PRE_l, float* __restrict__ PRE_g, float* __restrict__ PRE_f)
{
    const int tid = threadIdx.x;
    const int o = tid & 127;
    const int gi = __builtin_amdgcn_readfirstlane(tid >> 7);
    const int p0 = blockIdx.x * NPAIR + gi * 4;
    int ivP[4], lpOff[4];
    float mP[4];
    #pragma unroll
    for (int i = 0; i < 4; ++i) {
        int p = p0 + i, b = p / T_SZ, t = p - b * T_SZ;
        ivP[i] = itime[b * S_SZ + t + 1];
        mP[i] = (t == 0) ? 0.f : 1.f;
        lpOff[i] = ((t == 0) ? p : p - 1) * DK;   // masked when t==0
    }
    const float* wl = Wl + o * 512;
    const float* wg = Wg + o * 512;
    const float bl0 = blv[o], bg0 = bgv[o];
    float al[4] = {bl0, bl0, bl0, bl0};
    float ag[4] = {bg0, bg0, bg0, bg0};
    // cols 0:128 -> lp (masked)
    #pragma unroll 4
    for (int k4 = 0; k4 < 32; ++k4) {
        f32x4 w  = *(const f32x4*)(wl + 4 * k4);
        f32x4 w2 = *(const f32x4*)(wg + 4 * k4);
        #pragma unroll
        for (int i = 0; i < 4; ++i) {
            f32x4 x = *(const f32x4*)(le_ws + lpOff[i] + 4 * k4);
            #pragma unroll
            for (int j = 0; j < 4; ++j) {
                float xv = x[j] * mP[i];
                al[i] += w[j] * xv;
                ag[i] += w2[j] * xv;
            }
        }
    }
    // cols 128:256 -> it
    #pragma unroll 4
    for (int k4 = 0; k4 < 32; ++k4) {
        f32x4 w  = *(const f32x4*)(wl + 128 + 4 * k4);
        f32x4 w2 = *(const f32x4*)(wg + 128 + 4 * k4);
        #pragma unroll
        for (int i = 0; i < 4; ++i) {
            f32x4 x = *(const f32x4*)(it_t + ivP[i] * DK + 4 * k4);
            #pragma unroll
            for (int j = 0; j < 4; ++j) {
                al[i] += w[j] * x[j];
                ag[i] += w2[j] * x[j];
            }
        }
    }
    // cols 256:384 -> lc
    #pragma unroll 4
    for (int k4 = 0; k4 < 32; ++k4) {
        f32x4 w  = *(const f32x4*)(wl + 256 + 4 * k4);
        f32x4 w2 = *(const f32x4*)(wg + 256 + 4 * k4);
        #pragma unroll
        for (int i = 0; i < 4; ++i) {
            f32x4 x = *(const f32x4*)(le_ws + (p0 + i) * DK + 4 * k4);
            #pragma unroll
            for (int j = 0; j < 4; ++j) {
                al[i] += w[j] * x[j];
                ag[i] += w2[j] * x[j];
            }
        }
    }
    // f-gate: Wf cols 256:384 on it
    const float bf0 = bfv[o];
    float af[4] = {bf0, bf0, bf0, bf0};
    const float* wf = Wf + o * 384 + 256;
    #pragma unroll 4
    for (int k4 = 0; k4 < 32; ++k4) {
        f32x4 w = *(const f32x4*)(wf + 4 * k4);
        #pragma unroll
        for (int i = 0; i < 4; ++i) {
            f32x4 x = *(const f32x4*)(it_t + ivP[i] * DK + 4 * k4);
            af[i] += w[0] * x[0] + w[1] * x[1] + w[2] * x[2] + w[3] * x[3];
        }
    }
    #pragma unroll
    for (int i = 0; i < 4; ++i) {
        size_t idx = (size_t)(p0 + i) * DK + o;
        PRE_l[idx] = al[i];
        PRE_g[idx] = ag[i];
        PRE_f[idx] = af[i];
    }
}

// ---------------------------------------------------------------------------
// Kernel C: sequential scan, 4-way skill-split. Exchange via single 8-byte
// packets {u32 seq, f32 partial} per d (relaxed agent-scope u64 atomics) --
// discovery and data in ONE L2 round trip; no flags, no vmcnt fence.
// Poll is throttled (s_sleep after 64 spins) and capped (fail loud, never
// hang a harness timeout). h~ summed in canonical q0..q3 order.
// Zf(t+1) computed in the publish->poll gap (hS stable there).
// ---------------------------------------------------------------------------
__global__ __launch_bounds__(512, 1) void k_main(
    const int* __restrict__ eid, const float* __restrict__ qmat,
    const float* __restrict__ Wl, const float* __restrict__ Wg,
    const float* __restrict__ Wf, const float* __restrict__ h0,
    const float* __restrict__ PRE_l, const float* __restrict__ PRE_g,
    const float* __restrict__ PRE_f, float* __restrict__ ht_ws,
    u64* __restrict__ xbuf)
{
    extern __shared__ char smem[];
    u16*   hS   = (u16*)smem;                    // 64*136*2  = 17408
    float* part = (float*)(smem + 17408);        // 128*68*4  = 34816 -> 52224
    u16*   htbf = (u16*)(smem + 52224);          // hi[128], lo[128] -> 52736
    u16*   LGb  = (u16*)(smem + 52736);          // hi[128], lo[128] -> 53248
    float* LGf  = (float*)(smem + 53248);        // 512 -> 53760
    float* cS   = (float*)(smem + 53760);        // 512 -> 54272

    const int b    = blockIdx.x;
    const int qid  = blockIdx.y;     // skill quarter this block owns
    const int tid  = threadIdx.x;
    const int w    = tid >> 6;
    const int lane = tid & 63;
    const int quad = lane >> 4;
    const int l4   = lane & 15;
    const int ih   = w & 1;          // d-half
    const int jh   = w >> 1;         // 16-skill group within this quarter

    u64* xq = xbuf + (size_t)b * 1024;   // [qid][slot][128] u64 packets
    const int qa = (qid + 1) & 3, qb2 = (qid + 2) & 3, qc = (qid + 3) & 3;

    // ---- persistent A-frags ----
    u16x8 afr[4][4];
    #pragma unroll
    for (int mt = 0; mt < 4; ++mt)
        #pragma unroll
        for (int kt = 0; kt < 4; ++kt) {
            const float* p = Wf + (64 * ih + 16 * mt + l4) * 384 + 32 * kt + quad * 8;
            afr[mt][kt] = cvt8(*(const f32x4*)p, *(const f32x4*)(p + 4));
        }
    u16x8 azf[2][4];
    #pragma unroll
    for (int mt = 0; mt < 2; ++mt)
        #pragma unroll
        for (int kt = 0; kt < 4; ++kt) {
            int d = 16 * w + 8 * mt + (l4 >> 1);
            const float* base = (l4 & 1) ? Wg : Wl;
            const float* p = base + d * 512 + 384 + 32 * kt + quad * 8;
            azf[mt][kt] = cvt8(*(const f32x4*)p, *(const f32x4*)(p + 4));
        }
    u16x8 acf[4];
    #pragma unroll
    for (int kt = 0; kt < 4; ++kt) {
        const float* p = Wf + (16 * w + l4) * 384 + 128 + 32 * kt + quad * 8;
        acf[kt] = cvt8(*(const f32x4*)p, *(const f32x4*)(p + 4));
    }

    // ---- h0 (own quarter) -> fp32 regs + bf16 LDS mirror ----
    const int sl = 16 * jh + l4;     // local skill row 0..63
    f32x4 hreg[4];
    #pragma unroll
    for (int mt = 0; mt < 4; ++mt) {
        int d0 = 64 * ih + 16 * mt + quad * 4;
        f32x4 hv = *(const f32x4*)(h0 + (SQTR * qid + sl) * DK + d0);
        hreg[mt] = hv;
        *(u16x4*)(hS + sl * RL + d0) = cvt4(hv);
    }

    float kvt = qmat[eid[b * S_SZ] * SKILL + SQTR * qid + sl];

    f32x4 accF[4];

    // ---- prologue: partial h~0, packet exchange, Zf(t=0) ----
    {
        float htp[16];
        #pragma unroll
        for (int mt = 0; mt < 4; ++mt)
            #pragma unroll
            for (int r = 0; r < 4; ++r)
                htp[mt * 4 + r] = kvt * hreg[mt][r];
        #pragma unroll
        for (int mt = 0; mt < 4; ++mt)
            #pragma unroll
            for (int r = 0; r < 4; ++r)
                part[(64 * ih + 16 * mt + quad * 4 + r) * PP + jh * 16 + l4] = htp[mt * 4 + r];
        __syncthreads();
        int d = tid >> 2, kq = tid & 3;
        const float* pp = part + d * PP + kq * 16;
        float v = 0.f;
        #pragma unroll
        for (int i4 = 0; i4 < 4; ++i4) {
            f32x4 x = *(const f32x4*)(pp + 4 * i4);
            v += x[0] + x[1] + x[2] + x[3];
        }
        v += __shfl_xor(v, 1, 64);
        v += __shfl_xor(v, 2, 64);
        if (kq == 0) {
            u64 pkt = ((u64)1u << 32) | (u64)__builtin_bit_cast(u32, v);
            __hip_atomic_store(xq + qid * 256 + 128 + d, pkt,
                               __ATOMIC_RELAXED, __HIP_MEMORY_SCOPE_AGENT);
        }
        asm volatile("" ::: "memory");
        #pragma unroll
        for (int mt = 0; mt < 4; ++mt)
            accF[mt] = (f32x4){0.f, 0.f, 0.f, 0.f};
        {
            const u16* bp = hS + sl * RL + quad * 8;
            u16x8 bfr[4];
            #pragma unroll
            for (int kt = 0; kt < 4; ++kt) bfr[kt] = *(const u16x8*)(bp + kt * 32);
            #pragma unroll
            for (int mt = 0; mt < 4; ++mt)
                #pragma unroll
                for (int kt = 0; kt < 4; ++kt)
                    accF[mt] = mfma16(afr[mt][kt], bfr[kt], accF[mt]);
        }
        if (kq == 0) {
            u64 pa, pb, pc;
            int spins = 0;
            do {
                pa = __hip_atomic_load(xq + qa * 256 + 128 + d, __ATOMIC_RELAXED, __HIP_MEMORY_SCOPE_AGENT);
                pb = __hip_atomic_load(xq + qb2 * 256 + 128 + d, __ATOMIC_RELAXED, __HIP_MEMORY_SCOPE_AGENT);
                pc = __hip_atomic_load(xq + qc * 256 + 128 + d, __ATOMIC_RELAXED, __HIP_MEMORY_SCOPE_AGENT);
                if ((u32)(pa >> 32) >= 1u && (u32)(pb >> 32) >= 1u && (u32)(pc >> 32) >= 1u) break;
                if (spins > 64) __builtin_amdgcn_s_sleep(1);
            } while (++spins < SPIN_CAP);
            float va = pval(pa), vb = pval(pb), vc = pval(pc);
            float v0 = (qid == 0) ? v : (qid == 3) ? va : (qid == 2) ? vb : vc;
            float v1 = (qid == 1) ? v : (qid == 0) ? va : (qid == 3) ? vb : vc;
            float v2 = (qid == 2) ? v : (qid == 1) ? va : (qid == 0) ? vb : vc;
            float v3 = (qid == 3) ? v : (qid == 2) ? va : (qid == 1) ? vb : vc;
            float vt = ((v0 + v1) + v2) + v3;
            float hf = (float)(__bf16)vt;
            htbf[d] = bfu(vt);
            htbf[128 + d] = bfu(vt - hf);
        }
        __syncthreads();
    }

    for (int t = 0; t < T_SZ; ++t) {
        const size_t tb = (size_t)(b * T_SZ + t) * DK;
        float kvn = qmat[eid[b * S_SZ + t + 1] * SKILL + SQTR * qid + sl];
        f32x2 pl[2], pg[2];
        #pragma unroll
        for (int mt = 0; mt < 2; ++mt) {
            int d0 = 16 * w + 8 * mt + 2 * quad;
            pl[mt] = *(const f32x2*)(PRE_l + tb + d0);
            pg[mt] = *(const f32x2*)(PRE_g + tb + d0);
        }
        f32x4 pf = *(const f32x4*)(PRE_f + tb + 16 * w + quad * 4);

        // ---- z-MFMA: [Wl4;Wg4] @ h~ (hi + lo) ----
        f32x4 accZ[2];
        accZ[0] = (f32x4){0.f, 0.f, 0.f, 0.f};
        accZ[1] = (f32x4){0.f, 0.f, 0.f, 0.f};
        #pragma unroll
        for (int kt = 0; kt < 4; ++kt) {
            u16x8 bh = *(const u16x8*)(htbf + 32 * kt + quad * 8);
            u16x8 bl = *(const u16x8*)(htbf + 128 + 32 * kt + quad * 8);
            #pragma unroll
            for (int mt = 0; mt < 2; ++mt) {
                accZ[mt] = mfma16(azf[mt][kt], bh, accZ[mt]);
                accZ[mt] = mfma16(azf[mt][kt], bl, accZ[mt]);
            }
        }
        #pragma unroll
        for (int mt = 0; mt < 2; ++mt) {
            u32 hpack = 0, lpack = 0;
            f32x2 fpack;
            #pragma unroll
            for (int rp = 0; rp < 2; ++rp) {
                float zl = accZ[mt][2 * rp] + pl[mt][rp];
                float zg = accZ[mt][2 * rp + 1] + pg[mt][rp];
                float LGv = sigm(zg) * (tanh_f(zl) + 1.f) * 0.5f;
                float hif = (float)(__bf16)LGv;
                hpack |= ((u32)bfu(LGv)) << (16 * rp);
                lpack |= ((u32)bfu(LGv - hif)) << (16 * rp);
                fpack[rp] = LGv;
            }
            if (l4 == 0) {
                int d0 = 16 * w + 8 * mt + 2 * quad;
                *(u32*)(LGb + d0) = hpack;
                *(u32*)(LGb + 128 + d0) = lpack;
                *(f32x2*)(LGf + d0) = fpack;
            }
        }
        __syncthreads();   // B: LG ready

        // ---- c-MFMA: Wf2 @ LG (hi+lo) ----
        {
            f32x4 accC = (f32x4){0.f, 0.f, 0.f, 0.f};
            #pragma unroll
            for (int kt = 0; kt < 4; ++kt) {
                u16x8 bh = *(const u16x8*)(LGb + 32 * kt + quad * 8);
                u16x8 bl = *(const u16x8*)(LGb + 128 + 32 * kt + quad * 8);
                accC = mfma16(acf[kt], bh, accC);
                accC = mfma16(acf[kt], bl, accC);
            }
            accC += pf;
            if (l4 == 0) *(f32x4*)(cS + 16 * w + quad * 4) = accC;
        }
        __syncthreads();   // C: c ready

        // ---- update (own quarter) ----
        float htp[16];
        #pragma unroll
        for (int mt = 0; mt < 4; ++mt) {
            int d0 = 64 * ih + 16 * mt + quad * 4;
            f32x4 lg = *(const f32x4*)(LGf + d0);
            f32x4 cc = *(const f32x4*)(cS + d0);
            f32x4 hv;
            #pragma unroll
            for (int r = 0; r < 4; ++r) {
                float f = sigm(accF[mt][r] + cc[r]);
                float hn = kvt * lg[r] + f * hreg[mt][r];
                hreg[mt][r] = hn;
                htp[mt * 4 + r] = kvn * hn;
                hv[r] = hn;
            }
            *(u16x4*)(hS + sl * RL + d0) = cvt4(hv);
        }
        #pragma unroll
        for (int mt = 0; mt < 4; ++mt)
            #pragma unroll
            for (int r = 0; r < 4; ++r)
                part[(64 * ih + 16 * mt + quad * 4 + r) * PP + jh * 16 + l4] = htp[mt * 4 + r];
        kvt = kvn;
        __syncthreads();   // E: partials + hS(t+1) ready

        // ---- reduce -> quarter-partial; packet publish; Zf(t+1); poll ----
        {
            int d = tid >> 2, kq = tid & 3;
            const float* pp = part + d * PP + kq * 16;
            float v = 0.f;
            #pragma unroll
            for (int i4 = 0; i4 < 4; ++i4) {
                f32x4 x = *(const f32x4*)(pp + 4 * i4);
                v += x[0] + x[1] + x[2] + x[3];
            }
            v += __shfl_xor(v, 1, 64);
            v += __shfl_xor(v, 2, 64);
            const int slot = t & 1;            // seq = t+2
            const u32 seq = (u32)(t + 2);
            if (kq == 0) {
                u64 pkt = ((u64)seq << 32) | (u64)__builtin_bit_cast(u32, v);
                __hip_atomic_store(xq + qid * 256 + slot * 128 + d, pkt,
                                   __ATOMIC_RELAXED, __HIP_MEMORY_SCOPE_AGENT);
            }
            asm volatile("" ::: "memory");
            // Zf for t+1 hides exchange latency
            #pragma unroll
            for (int mt = 0; mt < 4; ++mt)
                accF[mt] = (f32x4){0.f, 0.f, 0.f, 0.f};
            {
                const u16* bp = hS + sl * RL + quad * 8;
                u16x8 bfr[4];
                #pragma unroll
                for (int kt = 0; kt < 4; ++kt) bfr[kt] = *(const u16x8*)(bp + kt * 32);
                #pragma unroll
                for (int mt = 0; mt < 4; ++mt)
                    #pragma unroll
                    for (int kt = 0; kt < 4; ++kt)
                        accF[mt] = mfma16(afr[mt][kt], bfr[kt], accF[mt]);
            }
            if (kq == 0) {
                u64 pa, pb, pc;
                int spins = 0;
                do {
                    pa = __hip_atomic_load(xq + qa * 256 + slot * 128 + d, __ATOMIC_RELAXED, __HIP_MEMORY_SCOPE_AGENT);
                    pb = __hip_atomic_load(xq + qb2 * 256 + slot * 128 + d, __ATOMIC_RELAXED, __HIP_MEMORY_SCOPE_AGENT);
                    pc = __hip_atomic_load(xq + qc * 256 + slot * 128 + d, __ATOMIC_RELAXED, __HIP_MEMORY_SCOPE_AGENT);
                    if ((u32)(pa >> 32) >= seq && (u32)(pb >> 32) >= seq && (u32)(pc >> 32) >= seq) break;
                    if (spins > 64) __builtin_amdgcn_s_sleep(1);
                } while (++spins < SPIN_CAP);
                float va = pval(pa), vb = pval(pb), vc = pval(pc);
                float v0 = (qid == 0) ? v : (qid == 3) ? va : (qid == 2) ? vb : vc;
                float v1 = (qid == 1) ? v : (qid == 0) ? va : (qid == 3) ? vb : vc;
                float v2 = (qid == 2) ? v : (qid == 1) ? va : (qid == 0) ? vb : vc;
                float v3 = (qid == 3) ? v : (qid == 2) ? va : (qid == 1) ? vb : vc;
                float vt = ((v0 + v1) + v2) + v3;
                float hf = (float)(__bf16)vt;
                htbf[d] = bfu(vt);
                htbf[128 + d] = bfu(vt - hf);
                if (qid == 0) ht_ws[tb + d] = vt;
            }
        }
        __syncthreads();   // TOP: h~ ready
    }
}

// ---------------------------------------------------------------------------
// Kernel D: pred. No LDS staging; x rows wave-uniform.
// ---------------------------------------------------------------------------
__global__ __launch_bounds__(256) void k_pred(
    const int* __restrict__ eid, const float* __restrict__ ex_t,
    const float* __restrict__ Wp, const float* __restrict__ bpv,
    const float* __restrict__ ht_ws, float* __restrict__ out)
{
    const int tid = threadIdx.x;
    const int o = tid & 127;
    const int gi = __builtin_amdgcn_readfirstlane(tid >> 7);
    const int p0 = blockIdx.x * NPAIR + gi * 4;
    int eP[4];
    #pragma unroll
    for (int i = 0; i < 4; ++i) {
        int p = p0 + i, b = p / T_SZ, t = p - b * T_SZ;
        eP[i] = eid[b * S_SZ + t + 1];
    }
    const float* wr = Wp + o * 256;
    const float bias = bpv[o];
    float acc[4] = {bias, bias, bias, bias};
    #pragma unroll 4
    for (int k4 = 0; k4 < 32; ++k4) {
        f32x4 w = *(const f32x4*)(wr + 4 * k4);
        #pragma unroll
        for (int i = 0; i < 4; ++i) {
            f32x4 x = *(const f32x4*)(ex_t + eP[i] * DK + 4 * k4);
            acc[i] += w[0] * x[0] + w[1] * x[1] + w[2] * x[2] + w[3] * x[3];
        }
    }
    #pragma unroll 4
    for (int k4 = 32; k4 < 64; ++k4) {
        f32x4 w = *(const f32x4*)(wr + 4 * k4);
        #pragma unroll
        for (int i = 0; i < 4; ++i) {
            f32x4 x = *(const f32x4*)(ht_ws + (size_t)(p0 + i) * DK + 4 * k4 - 128);
            acc[i] += w[0] * x[0] + w[1] * x[1] + w[2] * x[2] + w[3] * x[3];
        }
    }
    #pragma unroll
    for (int i = 0; i < 4; ++i)
        out[(size_t)(p0 + i) * DK + o] = sigm(acc[i]);
}

extern "C" void kernel_launch(void* const* d_in, const int* in_sizes, int n_in,
                              void* d_out, int out_size, void* d_ws, size_t ws_size,
                              hipStream_t stream) {
    const int* eid     = (const int*)d_in[0];
    const int* atime   = (const int*)d_in[1];
    const int* itime   = (const int*)d_in[2];
    const int* ansv    = (const int*)d_in[3];
    const float* qmat  = (const float*)d_in[4];
    const float* ex_t  = (const float*)d_in[5];
    const float* at_t  = (const float*)d_in[6];
    const float* it_t  = (const float*)d_in[7];
    const float* W1    = (const float*)d_in[8];
    const float* b1    = (const float*)d_in[9];
    const float* Wl    = (const float*)d_in[10];
    const float* blv   = (const float*)d_in[11];
    const float* Wg    = (const float*)d_in[12];
    const float* bgv   = (const float*)d_in[13];
    const float* Wf    = (const float*)d_in[14];
    const float* bfv   = (const float*)d_in[15];
    const float* Wp    = (const float*)d_in[16];
    const float* bpv   = (const float*)d_in[17];
    const float* h0    = (const float*)d_in[18];
    float* out = (float*)d_out;

    const size_t SZ = (size_t)B_SZ * T_SZ * DK;
    float* wsf   = (float*)d_ws;
    float* le_ws = wsf;
    float* PRE_l = wsf + SZ;
    float* PRE_g = wsf + 2 * SZ;
    float* PRE_f = wsf + 3 * SZ;
    float* ht_ws = wsf + 4 * SZ;
    // le_ws is dead after k_pre -> reuse its head for the packet buffer.
    u64* xbuf = (u64*)le_ws;                   // 32*4*2*128 u64 = 256 KiB

    hipFuncSetAttribute((const void*)k_main,
                        hipFuncAttributeMaxDynamicSharedMemorySize, 86016);

    dim3 gaux(508);
    k_le  <<<gaux, 256, 0, stream>>>(eid, atime, ansv, ex_t, at_t, W1, b1, le_ws);
    k_pre <<<gaux, 256, 0, stream>>>(itime, it_t, Wl, blv, Wg, bgv, Wf, bfv,
                                     le_ws, PRE_l, PRE_g, PRE_f);
    // re-arm packet buffer each replay (stale seq from prior replay otherwise)
    hipMemsetAsync(xbuf, 0, (size_t)B_SZ * 1024 * sizeof(u64), stream);
    k_main<<<dim3(B_SZ, 4), 512, 86016, stream>>>(eid, qmat, Wl, Wg, Wf, h0,
                                                  PRE_l, PRE_g, PRE_f, ht_ws,
                                                  xbuf);
    k_pred<<<gaux, 256, 0, stream>>>(eid, ex_t, Wp, bpv, ht_ws, out);
}